// Round 4
// baseline (233.472 us; speedup 1.0000x reference)
//
#include <hip/hip_runtime.h>

// Problem constants: B=8, N=16384, S=1024, T=2, D=3
#define NPTS 16384
#define SPTS 1024

typedef _Float16 half8 __attribute__((ext_vector_type(8)));
typedef float float16 __attribute__((ext_vector_type(16)));

union H8 { _Float16 h[8]; half8 v; uint4 q4; };

// min across each 32-lane half (validated r6/r7, absmax 0)
__device__ inline float wave32_min(float v) {
    v = fminf(v, __int_as_float(__builtin_amdgcn_mov_dpp(__float_as_int(v), 0xB1, 0xF, 0xF, true)));
    v = fminf(v, __int_as_float(__builtin_amdgcn_mov_dpp(__float_as_int(v), 0x4E, 0xF, 0xF, true)));
    v = fminf(v, __int_as_float(__builtin_amdgcn_mov_dpp(__float_as_int(v), 0x141, 0xF, 0xF, true)));
    v = fminf(v, __int_as_float(__builtin_amdgcn_mov_dpp(__float_as_int(v), 0x140, 0xF, 0xF, true)));
    v = fminf(v, __int_as_float(__builtin_amdgcn_ds_swizzle(__float_as_int(v), 0x401F)));
    return v;
}

// 3-way min shaped for LLVM's v_min3_f32 fusion (no inline asm: r9 hazard lesson).
__device__ inline float min3f(float a, float b, float c) {
    return fminf(fminf(a, b), c);
}

// Workspace layout (bytes):
//  [0..128)    counters: [0]=master, [1+bb]=per-bb (25 u32) — memset 128B each run
//  [128..3552) partials[856]: [0..832) per-block sums, [832..856) per-bb col-sums
//  [4096..102400)  minarr[24576] u32 — mode-0 fallback only (0x7F memset)
//  [102400.. )     slab: fp32 [24][32][1024] (3MB, mode 2) or fp16 (1.5MB, mode 1)
#define PART_OFF 128
#define MINARR_OFF 4096
#define SLAB_OFF 102400
#define NEED32 (SLAB_OFF + 24 * 32 * 1024 * 4)
#define NEED16 (SLAB_OFF + 24 * 32 * 1024 * 2)

// r12: (a) cm[32] per-thread array -> per-wave LDS colbuf (r11 counters: 212MB HBM
// traffic/dispatch at 84 VGPR vs ~130 live = scratch-spill suspicion; the RMW of a
// spilled cm[] is ~200MB of scratch traffic). Lanes<32 own tile t, lanes>=32 own
// t+1 after shfl_xor(32) merge -> divergence-free conflict-free LDS RMW.
// (b) reduce kernel folded in via per-bb + master completion counters -> 2 ops.
// (c) back to 2-deep MFMA (r8 lesson: spill cliff is catastrophic; 4-deep gave
// no MfmaUtil gain anyway at 7%).

__global__ __launch_bounds__(256, 3) void fused_kernel(
    const float* __restrict__ gt,   // [8,16384,3]
    const float* __restrict__ sp,   // [8,1024,3]
    const float* __restrict__ tgt,  // [16,16384,3]
    const float* __restrict__ tsp,  // [16,1024,3]
    const float* __restrict__ tm,   // [2,3,3]
    unsigned int* __restrict__ counters,  // [0]=master, [1+bb]=bb done-count
    float* __restrict__ partials,         // [856]
    unsigned int* __restrict__ minarr,
    float* __restrict__ slab32,
    _Float16* __restrict__ slab16,
    float* __restrict__ out,
    int mode)
{
    const int bid = blockIdx.x;
    const int tid = threadIdx.x;
    const int lane = tid & 63;
    const int lh = lane & 31;
    const int w = tid >> 6;  // wave 0..3

    __shared__ uint4 s_frag4[1584];   // sp frags [0,1056) + gt frags [1056,1584) = 25.3 KB
    __shared__ float colLds[4096];    // per-wave col-min [w][t*32+col], 16 KB
    __shared__ float redbuf[4];
    __shared__ int flag;

    if (bid >= 768) {
        // ---------------- consistency MSE (fp32 exact), tail blocks ----------------
        int idx = (bid - 768) * 256 + tid;  // over (t,b,s) = 2*8*1024
        int t = idx >> 13;
        int bs = idx & 8191;
        const float* p = sp + (size_t)bs * 3;
        float x = p[0], y = p[1], z = p[2];
        const float* m = tm + t * 9;
        const float* q = tsp + (size_t)idx * 3;
        float acc = 0.f;
#pragma unroll
        for (int e = 0; e < 3; e++) {
            float v = fmaf(x, m[e], fmaf(y, m[3 + e], z * m[6 + e]));
            float d = v - q[e];
            acc = fmaf(d, d, acc);
        }
        for (int o = 32; o > 0; o >>= 1) acc += __shfl_down(acc, o, 64);
        if (lane == 0) redbuf[w] = acc;
        __syncthreads();
        if (tid == 0) {
            partials[bid] = (redbuf[0] + redbuf[1] + redbuf[2] + redbuf[3])
                            * (1000.f / (2.f * 8.f * 1024.f * 3.f));
            __threadfence();
            unsigned int old = atomicAdd(&counters[0], 1u);
            flag = (old == 831u);
        }
        __syncthreads();
        if (flag) {
            __threadfence();
            float s2 = 0.f;
            for (int i = tid; i < 856; i += 256) s2 += partials[i];
            for (int o = 32; o > 0; o >>= 1) s2 += __shfl_down(s2, o, 64);
            if (lane == 0) redbuf[w] = s2;
            __syncthreads();
            if (tid == 0) out[0] = redbuf[0] + redbuf[1] + redbuf[2] + redbuf[3];
        }
        return;
    }

    // ---------------- fused chamfer: one D matrix, both mins ----------------
    int bb = bid >> 5;         // 24 batches
    int mc = bid & 31;         // 512-row gt chunk
    const float* spp = (bb < 8) ? sp + (size_t)bb * SPTS * 3
                                : tsp + (size_t)(bb - 8) * SPTS * 3;
    const float* qp  = (bb < 8) ? gt + (size_t)bb * NPTS * 3
                                : tgt + (size_t)(bb - 8) * NPTS * 3;

    // zero slots for all 48 tiles (32 sp + 16 gt): index t*33+32
    if (tid < 48) s_frag4[tid * 33 + 32] = make_uint4(0, 0, 0, 0);
    // init per-wave col-min buffers
    for (int i = tid; i < 4096; i += 256) colLds[i] = 1e30f;
    // stage sp B-frags (1024 points)
    for (int i = tid; i < 1024; i += 256) {
        const float* pp = spp + (size_t)i * 3;
        float sx = pp[0], sy = pp[1], sz = pp[2];
        H8 bf; bf.q4 = make_uint4(0, 0, 0, 0);
        bf.h[0] = (_Float16)(-2.f * sx); bf.h[1] = (_Float16)(-2.f * sy);
        bf.h[2] = (_Float16)(-2.f * sz); bf.h[3] = (_Float16)1.f;
        bf.h[4] = (_Float16)(sx * sx + sy * sy + sz * sz);
        s_frag4[(i >> 5) * 33 + (i & 31)] = bf.q4;
    }
    // stage gt A-frags (512 points of this chunk)
    for (int i = tid; i < 512; i += 256) {
        const float* pp = qp + (size_t)(mc * 512 + i) * 3;
        float x = pp[0], y = pp[1], z = pp[2];
        H8 af; af.q4 = make_uint4(0, 0, 0, 0);
        af.h[0] = (_Float16)x; af.h[1] = (_Float16)y; af.h[2] = (_Float16)z;
        af.h[3] = (_Float16)(x * x + y * y + z * z); af.h[4] = (_Float16)1.f;
        s_frag4[1056 + (i >> 5) * 33 + (i & 31)] = af.q4;
    }
    __syncthreads();

    const char* lds = (const char*)s_frag4;
    const int laneoff = (lane < 32) ? lh * 16 : 512;
    const char* bBase = lds + laneoff;
    const char* aBase = lds + 1056 * 16 + laneoff;

    float16 z16 = {0.f,0.f,0.f,0.f,0.f,0.f,0.f,0.f,0.f,0.f,0.f,0.f,0.f,0.f,0.f,0.f};
    float* myCol = colLds + w * 1024 + lh;     // + (t + thalf)*32 per update
    const int thalf = (lane < 32) ? 0 : 1;     // lanes<32 own tile t, >=32 own t+1
    float wsum = 0.f;

    for (int mi = 0; mi < 4; mi++) {
        int mt = w * 4 + mi;  // this wave's m-tile (0..15)
        H8 a; a.q4 = *(const uint4*)(aBase + mt * 528);
        float rm[16];
#pragma unroll
        for (int r = 0; r < 16; r++) rm[r] = 1e30f;
#pragma unroll
        for (int t = 0; t < 32; t += 2) {
            H8 b0; b0.q4 = *(const uint4*)(bBase + t * 528);
            H8 b1; b1.q4 = *(const uint4*)(bBase + (t + 1) * 528);
            float16 d0 = __builtin_amdgcn_mfma_f32_32x32x16_f16(a.v, b0.v, z16, 0, 0, 0);
            float16 d1 = __builtin_amdgcn_mfma_f32_32x32x16_f16(a.v, b1.v, z16, 0, 0, 0);
            // row-min accumulate (gt side)
#pragma unroll
            for (int r = 0; r < 16; r++) rm[r] = min3f(rm[r], d0[r], d1[r]);
            // col-min (sp side): 16-row chain per tile, merge halves, LDS RMW
            float g0 = min3f(d0[0],  d0[1],  d0[2]);
            float g1 = min3f(d0[3],  d0[4],  d0[5]);
            float g2 = min3f(d0[6],  d0[7],  d0[8]);
            float g3 = min3f(d0[9],  d0[10], d0[11]);
            float g4 = min3f(d0[12], d0[13], d0[14]);
            float v0 = min3f(min3f(g0, g1, g2), g4, fminf(g3, d0[15]));
            float h0 = min3f(d1[0],  d1[1],  d1[2]);
            float h1 = min3f(d1[3],  d1[4],  d1[5]);
            float h2 = min3f(d1[6],  d1[7],  d1[8]);
            float h3 = min3f(d1[9],  d1[10], d1[11]);
            float h4 = min3f(d1[12], d1[13], d1[14]);
            float v1 = min3f(min3f(h0, h1, h2), h4, fminf(h3, d1[15]));
            v0 = fminf(v0, __shfl_xor(v0, 32, 64));
            v1 = fminf(v1, __shfl_xor(v1, 32, 64));
            float vv = (lane < 32) ? v0 : v1;
            float* p = myCol + (t + thalf) * 32;
            *p = fminf(*p, vv);
        }
        float tsum = 0.f;
#pragma unroll
        for (int r = 0; r < 16; r++) tsum += wave32_min(rm[r]);
        wsum += tsum;
    }
    wsum += __shfl_xor(wsum, 32, 64);
    if (lane == 0) redbuf[w] = wsum;
    __syncthreads();
    if (tid == 0) {
        float scale = (bb < 8) ? 1.f / (2.f * 3.f * 8.f * 16384.f)
                               : 1.f / (2.f * 3.f * 16.f * 16384.f);
        partials[bid] = (redbuf[0] + redbuf[1] + redbuf[2] + redbuf[3]) * scale;
    }

    // ---- cross-wave col-min combine -> slab (plain stores) or atomic fallback ----
#pragma unroll
    for (int k = 0; k < 4; k++) {
        int e = k * 256 + tid;  // e = t*32 + col
        float v = fminf(fminf(colLds[e], colLds[1024 + e]),
                        fminf(colLds[2048 + e], colLds[3072 + e]));
        size_t si = ((size_t)(bb * 32 + mc)) * 1024 + e;
        if (mode == 2)      slab32[si] = v;
        else if (mode == 1) slab16[si] = (_Float16)v;
        else                atomicMin(&minarr[bb * SPTS + e], __float_as_uint(fmaxf(v, 0.f)));
    }

    // ---- per-bb epilogue: last of 32 blocks finalizes this bb's col-min sum ----
    __threadfence();
    if (tid == 0) {
        unsigned int old = atomicAdd(&counters[1 + bb], 1u);
        flag = (old == 31u);
    }
    __syncthreads();
    if (flag) {
        __threadfence();  // acquire: other blocks' slab/minarr stores
        float scale = (bb < 8) ? 1.f / (2.f * 3.f * 8.f * 1024.f)
                               : 1.f / (2.f * 3.f * 16.f * 1024.f);
        float s = 0.f;
#pragma unroll
        for (int k = 0; k < 4; k++) {
            int e = k * 256 + tid;
            float v;
            if (mode == 2) {
                v = 1e30f;
#pragma unroll 8
                for (int r = 0; r < 32; r++)
                    v = fminf(v, slab32[((size_t)(bb * 32 + r)) * 1024 + e]);
            } else if (mode == 1) {
                v = 1e30f;
#pragma unroll 8
                for (int r = 0; r < 32; r++)
                    v = fminf(v, (float)slab16[((size_t)(bb * 32 + r)) * 1024 + e]);
            } else {
                v = __uint_as_float(minarr[bb * SPTS + e]);
            }
            s += v * scale;
        }
        for (int o = 32; o > 0; o >>= 1) s += __shfl_down(s, o, 64);
        if (lane == 0) redbuf[w] = s;
        __syncthreads();
        if (tid == 0) partials[832 + bb] = redbuf[0] + redbuf[1] + redbuf[2] + redbuf[3];
    }

    // ---- master counter: very last block sums all 856 partials -> out ----
    __syncthreads();
    if (tid == 0) {
        __threadfence();
        unsigned int old = atomicAdd(&counters[0], 1u);
        flag = (old == 831u);
    }
    __syncthreads();
    if (flag) {
        __threadfence();
        float s2 = 0.f;
        for (int i = tid; i < 856; i += 256) s2 += partials[i];
        for (int o = 32; o > 0; o >>= 1) s2 += __shfl_down(s2, o, 64);
        if (lane == 0) redbuf[w] = s2;
        __syncthreads();
        if (tid == 0) out[0] = redbuf[0] + redbuf[1] + redbuf[2] + redbuf[3];
    }
}

extern "C" void kernel_launch(void* const* d_in, const int* in_sizes, int n_in,
                              void* d_out, int out_size, void* d_ws, size_t ws_size,
                              hipStream_t stream) {
    const float* gt  = (const float*)d_in[0];  // gt_points [8,16384,3]
    const float* sp  = (const float*)d_in[1];  // structure_points [8,1024,3]
    const float* tgt = (const float*)d_in[2];  // transed_gt_points [2,8,16384,3]
    const float* tsp = (const float*)d_in[3];  // transed_structure_points [2,8,1024,3]
    const float* tm  = (const float*)d_in[4];  // trans_mats [2,3,3]

    unsigned int* counters = (unsigned int*)d_ws;
    float* partials = (float*)((char*)d_ws + PART_OFF);
    unsigned int* minarr = (unsigned int*)((char*)d_ws + MINARR_OFF);
    float* slab32 = (float*)((char*)d_ws + SLAB_OFF);
    _Float16* slab16 = (_Float16*)((char*)d_ws + SLAB_OFF);

    int mode = (ws_size >= (size_t)NEED32) ? 2
             : ((ws_size >= (size_t)NEED16) ? 1 : 0);  // constant per ws_size (graph-safe)

    hipMemsetAsync(d_ws, 0, 128, stream);  // master + per-bb counters
    if (mode == 0)
        hipMemsetAsync(minarr, 0x7F, 24 * 1024 * sizeof(unsigned int), stream);

    fused_kernel<<<832, 256, 0, stream>>>(gt, sp, tgt, tsp, tm, counters, partials,
                                          minarr, slab32, slab16, (float*)d_out, mode);
}

// Round 5
// 145.796 us; speedup vs baseline: 1.6014x; 1.6014x over previous
//
#include <hip/hip_runtime.h>

// Problem constants: B=8, N=16384, S=1024, T=2, D=3
#define NPTS 16384
#define SPTS 1024

typedef _Float16 half8 __attribute__((ext_vector_type(8)));
typedef float float16 __attribute__((ext_vector_type(16)));

union H8 { _Float16 h[8]; half8 v; uint4 q4; };

// min across each 32-lane half (validated r6/r7, absmax 0)
__device__ inline float wave32_min(float v) {
    v = fminf(v, __int_as_float(__builtin_amdgcn_mov_dpp(__float_as_int(v), 0xB1, 0xF, 0xF, true)));
    v = fminf(v, __int_as_float(__builtin_amdgcn_mov_dpp(__float_as_int(v), 0x4E, 0xF, 0xF, true)));
    v = fminf(v, __int_as_float(__builtin_amdgcn_mov_dpp(__float_as_int(v), 0x141, 0xF, 0xF, true)));
    v = fminf(v, __int_as_float(__builtin_amdgcn_mov_dpp(__float_as_int(v), 0x140, 0xF, 0xF, true)));
    v = fminf(v, __int_as_float(__builtin_amdgcn_ds_swizzle(__float_as_int(v), 0x401F)));
    return v;
}

// 3-way min shaped for LLVM's v_min3_f32 fusion (no inline asm: r9 hazard lesson).
__device__ inline float min3f(float a, float b, float c) {
    return fminf(fminf(a, b), c);
}

// r13 REDESIGN. r12 counters: WRITE 49MB == atomicMin fallback -> ws_size < 1.7MB,
// slab tiers NEVER engaged; 786K device-scope atomics (execute past L2) were the
// dominant HBM traffic all along. Also inner-loop LDS RMW for col-min was a serial
// latency chain (178us, VALUBusy 11%).
// Fix: two passes, each with its reduction axis block-local. Distances computed
// twice (MFMA was 3% utilized -- compute is free):
//   blocks [0,768):    row pass. bb=bid>>5, mc=bid&31: 512 gt rows x all 1024 sp.
//                      min over sp per gt row (block-local), sum -> partials[bid].
//   blocks [768,1536): col pass. bb=c>>5, sc=c&31: 32 sp points x all 16384 gt,
//                      staged in 16 LDS rounds. min over gt per sp point
//                      (block-local), sum -> partials[bid].
//   blocks [1536,1600): consistency MSE -> partials[bid].
// Master completion counter: last of 1600 blocks sums partials -> out.
// No atomics (except 1 counter add/block), no slab, no minarr. WS need: 6.5KB.
// Inner loop: 2 ds_read_b128 + 2 MFMA + 16 min3. No per-thread arrays beyond
// rm[16] (r8 lesson: spill cliff; (256,3) cap 170 VGPR, est ~90 here).

__global__ __launch_bounds__(256, 3) void fused_kernel(
    const float* __restrict__ gt,   // [8,16384,3]
    const float* __restrict__ sp,   // [8,1024,3]
    const float* __restrict__ tgt,  // [16,16384,3]
    const float* __restrict__ tsp,  // [16,1024,3]
    const float* __restrict__ tm,   // [2,3,3]
    unsigned int* __restrict__ counters,  // [0]=master
    float* __restrict__ partials,         // [1600]
    float* __restrict__ out)
{
    const int bid = blockIdx.x;
    const int tid = threadIdx.x;
    const int lane = tid & 63;
    const int lh = lane & 31;
    const int w = tid >> 6;  // wave 0..3

    __shared__ uint4 s_frag4[1584];  // B tiles [0,1056) + A tiles [1056,1584) = 25.3 KB
    __shared__ float redbuf[4];
    __shared__ float cmerge[128];    // col pass: [wave][32] per-sp mins
    __shared__ int flag;

    float16 z16 = {0.f,0.f,0.f,0.f,0.f,0.f,0.f,0.f,0.f,0.f,0.f,0.f,0.f,0.f,0.f,0.f};

    if (bid >= 1536) {
        // ---------------- consistency MSE (fp32 exact), 64 blocks ----------------
        int idx = (bid - 1536) * 256 + tid;  // over (t,b,s) = 2*8*1024
        int t = idx >> 13;
        int bs = idx & 8191;
        const float* p = sp + (size_t)bs * 3;
        float x = p[0], y = p[1], z = p[2];
        const float* m = tm + t * 9;
        const float* q = tsp + (size_t)idx * 3;
        float acc = 0.f;
#pragma unroll
        for (int e = 0; e < 3; e++) {
            float v = fmaf(x, m[e], fmaf(y, m[3 + e], z * m[6 + e]));
            float d = v - q[e];
            acc = fmaf(d, d, acc);
        }
        for (int o = 32; o > 0; o >>= 1) acc += __shfl_down(acc, o, 64);
        if (lane == 0) redbuf[w] = acc;
        __syncthreads();
        if (tid == 0)
            partials[bid] = (redbuf[0] + redbuf[1] + redbuf[2] + redbuf[3])
                            * (1000.f / (2.f * 8.f * 1024.f * 3.f));
    } else if (bid < 768) {
        // ---------------- row pass: gt-side min (over sp), block-local ----------------
        int bb = bid >> 5;         // 24 batches
        int mc = bid & 31;         // 512-row gt chunk
        const float* spp = (bb < 8) ? sp + (size_t)bb * SPTS * 3
                                    : tsp + (size_t)(bb - 8) * SPTS * 3;
        const float* qp  = (bb < 8) ? gt + (size_t)bb * NPTS * 3
                                    : tgt + (size_t)(bb - 8) * NPTS * 3;

        // zero slots for all 48 tiles (32 sp B + 16 gt A)
        if (tid < 48) s_frag4[tid * 33 + 32] = make_uint4(0, 0, 0, 0);
        // stage sp B-frags (1024 points)
        for (int i = tid; i < 1024; i += 256) {
            const float* pp = spp + (size_t)i * 3;
            float sx = pp[0], sy = pp[1], sz = pp[2];
            H8 bf; bf.q4 = make_uint4(0, 0, 0, 0);
            bf.h[0] = (_Float16)(-2.f * sx); bf.h[1] = (_Float16)(-2.f * sy);
            bf.h[2] = (_Float16)(-2.f * sz); bf.h[3] = (_Float16)1.f;
            bf.h[4] = (_Float16)(sx * sx + sy * sy + sz * sz);
            s_frag4[(i >> 5) * 33 + (i & 31)] = bf.q4;
        }
        // stage gt A-frags (512 points of this chunk)
        for (int i = tid; i < 512; i += 256) {
            const float* pp = qp + (size_t)(mc * 512 + i) * 3;
            float x = pp[0], y = pp[1], z = pp[2];
            H8 af; af.q4 = make_uint4(0, 0, 0, 0);
            af.h[0] = (_Float16)x; af.h[1] = (_Float16)y; af.h[2] = (_Float16)z;
            af.h[3] = (_Float16)(x * x + y * y + z * z); af.h[4] = (_Float16)1.f;
            s_frag4[1056 + (i >> 5) * 33 + (i & 31)] = af.q4;
        }
        __syncthreads();

        const char* lds = (const char*)s_frag4;
        const int laneoff = (lane < 32) ? lh * 16 : 512;
        const char* bBase = lds + laneoff;
        const char* aBase = lds + 1056 * 16 + laneoff;

        float wsum = 0.f;
        for (int mi = 0; mi < 4; mi++) {
            int mt = w * 4 + mi;  // this wave's m-tile (0..15)
            H8 a; a.q4 = *(const uint4*)(aBase + mt * 528);
            float rm[16];
#pragma unroll
            for (int r = 0; r < 16; r++) rm[r] = 1e30f;
#pragma unroll
            for (int t = 0; t < 32; t += 2) {
                H8 b0; b0.q4 = *(const uint4*)(bBase + t * 528);
                H8 b1; b1.q4 = *(const uint4*)(bBase + (t + 1) * 528);
                float16 d0 = __builtin_amdgcn_mfma_f32_32x32x16_f16(a.v, b0.v, z16, 0, 0, 0);
                float16 d1 = __builtin_amdgcn_mfma_f32_32x32x16_f16(a.v, b1.v, z16, 0, 0, 0);
#pragma unroll
                for (int r = 0; r < 16; r++) rm[r] = min3f(rm[r], d0[r], d1[r]);
            }
            float tsum = 0.f;
#pragma unroll
            for (int r = 0; r < 16; r++) tsum += wave32_min(rm[r]);
            wsum += tsum;
        }
        wsum += __shfl_xor(wsum, 32, 64);
        if (lane == 0) redbuf[w] = wsum;
        __syncthreads();
        if (tid == 0) {
            float scale = (bb < 8) ? 1.f / (2.f * 3.f * 8.f * 16384.f)
                                   : 1.f / (2.f * 3.f * 16.f * 16384.f);
            partials[bid] = (redbuf[0] + redbuf[1] + redbuf[2] + redbuf[3]) * scale;
        }
    } else {
        // ---------------- col pass: sp-side min (over gt), block-local ----------------
        int c = bid - 768;
        int bb = c >> 5;           // 24 batches
        int sc = c & 31;           // 32-point sp chunk
        const float* spp = (bb < 8) ? sp + (size_t)bb * SPTS * 3
                                    : tsp + (size_t)(bb - 8) * SPTS * 3;
        const float* qp  = (bb < 8) ? gt + (size_t)bb * NPTS * 3
                                    : tgt + (size_t)(bb - 8) * NPTS * 3;

        // zero slots: 32 B tiles + 1 A tile
        if (tid < 33) s_frag4[(tid < 32) ? (tid * 33 + 32) : 1088] = make_uint4(0, 0, 0, 0);
        // stage A-frags: this block's 32 sp points (A format: [x,y,z,|p|^2,1])
        if (tid < 32) {
            const float* pp = spp + (size_t)(sc * 32 + tid) * 3;
            float sx = pp[0], sy = pp[1], sz = pp[2];
            H8 af; af.q4 = make_uint4(0, 0, 0, 0);
            af.h[0] = (_Float16)sx; af.h[1] = (_Float16)sy; af.h[2] = (_Float16)sz;
            af.h[3] = (_Float16)(sx * sx + sy * sy + sz * sz); af.h[4] = (_Float16)1.f;
            s_frag4[1056 + tid] = af.q4;
        }

        const char* lds = (const char*)s_frag4;
        const int laneoff = (lane < 32) ? lh * 16 : 512;
        const char* bBase = lds + laneoff;
        const char* aBase = lds + 1056 * 16 + laneoff;

        H8 a;
        float rm[16];
#pragma unroll
        for (int r = 0; r < 16; r++) rm[r] = 1e30f;

        for (int g = 0; g < 16; g++) {
            if (g) __syncthreads();  // protect B-region overwrite
            // stage gt B-frags: points [g*1024, g*1024+1024)
            for (int i = tid; i < 1024; i += 256) {
                const float* pp = qp + (size_t)(g * 1024 + i) * 3;
                float x = pp[0], y = pp[1], z = pp[2];
                H8 bf; bf.q4 = make_uint4(0, 0, 0, 0);
                bf.h[0] = (_Float16)(-2.f * x); bf.h[1] = (_Float16)(-2.f * y);
                bf.h[2] = (_Float16)(-2.f * z); bf.h[3] = (_Float16)1.f;
                bf.h[4] = (_Float16)(x * x + y * y + z * z);
                s_frag4[(i >> 5) * 33 + (i & 31)] = bf.q4;
            }
            __syncthreads();
            if (g == 0) a.q4 = *(const uint4*)aBase;  // sp A-frag, loaded once
            const char* wB = bBase + (size_t)(w * 8) * 528;  // wave's 8 n-tiles
#pragma unroll
            for (int j = 0; j < 8; j += 2) {
                H8 b0; b0.q4 = *(const uint4*)(wB + j * 528);
                H8 b1; b1.q4 = *(const uint4*)(wB + (j + 1) * 528);
                float16 d0 = __builtin_amdgcn_mfma_f32_32x32x16_f16(a.v, b0.v, z16, 0, 0, 0);
                float16 d1 = __builtin_amdgcn_mfma_f32_32x32x16_f16(a.v, b1.v, z16, 0, 0, 0);
#pragma unroll
                for (int r = 0; r < 16; r++) rm[r] = min3f(rm[r], d0[r], d1[r]);
            }
        }
        // per-wave: min over lanes (gt cols) -> 32 per-sp values; merge 4 waves
        float wm[16];
#pragma unroll
        for (int r = 0; r < 16; r++) wm[r] = wave32_min(rm[r]);
        if (lh == 0) {
            int halfo = (lane >> 5) * 4;
#pragma unroll
            for (int r = 0; r < 16; r++)
                cmerge[w * 32 + (r & 3) + 8 * (r >> 2) + halfo] = wm[r];
        }
        __syncthreads();
        if (tid < 32) {
            float v = fminf(fminf(cmerge[tid], cmerge[32 + tid]),
                            fminf(cmerge[64 + tid], cmerge[96 + tid]));
            float scale = (bb < 8) ? 1.f / (2.f * 3.f * 8.f * 1024.f)
                                   : 1.f / (2.f * 3.f * 16.f * 1024.f);
            float s = v * scale;
            for (int o = 16; o > 0; o >>= 1) s += __shfl_xor(s, o, 32);
            if (tid == 0) partials[bid] = s;
        }
    }

    // ---------------- master counter: last block sums all partials -> out ----------------
    __syncthreads();
    if (tid == 0) {
        __threadfence();
        unsigned int old = atomicAdd(&counters[0], 1u);
        flag = (old == 1599u);
    }
    __syncthreads();
    if (flag) {
        __threadfence();
        float s2 = 0.f;
        for (int i = tid; i < 1600; i += 256) s2 += partials[i];
        for (int o = 32; o > 0; o >>= 1) s2 += __shfl_down(s2, o, 64);
        if (lane == 0) redbuf[w] = s2;
        __syncthreads();
        if (tid == 0) out[0] = redbuf[0] + redbuf[1] + redbuf[2] + redbuf[3];
    }
}

extern "C" void kernel_launch(void* const* d_in, const int* in_sizes, int n_in,
                              void* d_out, int out_size, void* d_ws, size_t ws_size,
                              hipStream_t stream) {
    const float* gt  = (const float*)d_in[0];  // gt_points [8,16384,3]
    const float* sp  = (const float*)d_in[1];  // structure_points [8,1024,3]
    const float* tgt = (const float*)d_in[2];  // transed_gt_points [2,8,16384,3]
    const float* tsp = (const float*)d_in[3];  // transed_structure_points [2,8,1024,3]
    const float* tm  = (const float*)d_in[4];  // trans_mats [2,3,3]

    unsigned int* counters = (unsigned int*)d_ws;
    float* partials = (float*)((char*)d_ws + 64);  // 1600 floats

    hipMemsetAsync(d_ws, 0, 64, stream);  // master counter

    fused_kernel<<<1600, 256, 0, stream>>>(gt, sp, tgt, tsp, tm, counters, partials,
                                           (float*)d_out);
}